// Round 11
// baseline (1255.770 us; speedup 1.0000x reference)
//
#include <hip/hip_runtime.h>
#include <hip/hip_bf16.h>

// GNN: 2-layer GraphConv (DGL norm='both'), N=100000, E=1600000.
// Round 11: per-node sort (k_sort2) fused away — aggregation runs directly on
// the bucket streams with per-bucket LDS accumulators. r5's version of this
// idea failed at 21% occupancy (4-wave blocks) with scalar loads; this one
// uses 1024-thread blocks (2/CU, 100% wave occupancy) and ushort2 gathers
// (one wave instr = 2 full bf16 rows). ds_add 4-way bank aliasing accepted
// (1.58x, m136). bf16 tables + fixed-cap binning kept.

#define BSH 7                 // 128 nodes per bucket
#define BNODES 128
#define SRCMASK 0x1FFFF       // src < 131072
#define CAP 2560              // bucket capacity (mean 2048, sigma~45)

__device__ __forceinline__ unsigned short f2bf(float f) {
    unsigned int u = __float_as_uint(f);
    return (unsigned short)((u + 0x7FFFu + ((u >> 16) & 1u)) >> 16);  // RNE
}

// ---------------- out-degree: 1 edge/thread, 100k-target atomics ------------
__global__ __launch_bounds__(256) void k_degO(const int* __restrict__ src,
        int* __restrict__ dO, int E) {
    int i = blockIdx.x * 256 + threadIdx.x;
    if (i < E) atomicAdd(&dO[src[i]], 1);
}

// ---------------- init line-padded bucket cursors ----------------
__global__ void k_initcur(int* __restrict__ bcur, int NB) {
    int t = blockIdx.x * 256 + threadIdx.x;
    if (t < NB) bcur[t * 16] = t * CAP;
}

// ---------------- place: bin edges into fixed-cap bucket regions ------------
__global__ __launch_bounds__(1024) void k_place(const int* __restrict__ src,
        const int* __restrict__ dst, int* __restrict__ bcur,
        int* __restrict__ ebuf, int E, int NB) {
    __shared__ int lh[800], lbase[800];
    int t = threadIdx.x;
    int e0 = blockIdx.x * 4096;
    int e1 = min(e0 + 4096, E);
    for (int i = t; i < NB; i += 1024) lh[i] = 0;
    __syncthreads();
    for (int i = e0 + t; i < e1; i += 1024) atomicAdd(&lh[dst[i] >> BSH], 1);
    __syncthreads();
    for (int i = t; i < NB; i += 1024) {
        int c = lh[i];
        if (c) lbase[i] = atomicAdd(&bcur[i * 16], c);
        lh[i] = 0;
    }
    __syncthreads();
    for (int i = e0 + t; i < e1; i += 1024) {
        int d = dst[i], b = d >> BSH;
        int pos = lbase[b] + atomicAdd(&lh[b], 1);
        ebuf[pos] = src[i] | ((d & (BNODES - 1)) << 17);
    }
}

// ---------------- GEMM1: h1(bf16) = (x*rsqrt(dO)) @ W1, 128->64 -------------
__global__ __launch_bounds__(256) void k_gemm1(const float* __restrict__ x,
                        const float* __restrict__ W1, const int* __restrict__ dO,
                        unsigned short* __restrict__ h1, int n) {
    __shared__ float sX[64 * 132];
    __shared__ float sW[128 * 64];
    const int t = threadIdx.x;
    {
        const float4* W4 = (const float4*)W1;
        float4* sW4 = (float4*)sW;
#pragma unroll
        for (int i = 0; i < 8; i++) sW4[t + 256 * i] = W4[t + 256 * i];
    }
    const int rowbase = blockIdx.x * 64;
    {
        const float4* x4 = (const float4*)x;
        float4* sX4 = (float4*)sX;
#pragma unroll
        for (int i = 0; i < 8; i++) {
            int f = t + 256 * i;
            int row = f >> 5, kc = f & 31;
            int grow = rowbase + row;
            float4 v = make_float4(0.f, 0.f, 0.f, 0.f);
            if (grow < n) v = x4[(size_t)grow * 32 + kc];
            sX4[row * 33 + kc] = v;
        }
    }
    __syncthreads();
    const int lane = t & 63, wv = t >> 6;
    const int rg = lane >> 2, cg = lane & 3;
    const int c0 = wv * 16 + cg * 4;
    float acc[4][4] = {};
    for (int kk = 0; kk < 128; kk += 4) {
        float xr[4][4], wr[4][4];
#pragma unroll
        for (int i = 0; i < 4; i++)
            *(float4*)xr[i] = *(const float4*)&sX[(rg + 16 * i) * 132 + kk];
#pragma unroll
        for (int j = 0; j < 4; j++)
            *(float4*)wr[j] = *(const float4*)&sW[(kk + j) * 64 + c0];
#pragma unroll
        for (int j = 0; j < 4; j++)
#pragma unroll
            for (int i = 0; i < 4; i++)
#pragma unroll
                for (int c = 0; c < 4; c++)
                    acc[i][c] = fmaf(xr[i][j], wr[j][c], acc[i][c]);
    }
#pragma unroll
    for (int i = 0; i < 4; i++) {
        int grow = rowbase + rg + 16 * i;
        if (grow < n) {
            float nf = rsqrtf(fmaxf((float)dO[grow], 1.0f));
            ushort4 o;
            o.x = f2bf(acc[i][0] * nf); o.y = f2bf(acc[i][1] * nf);
            o.z = f2bf(acc[i][2] * nf); o.w = f2bf(acc[i][3] * nf);
            *(ushort4*)&h1[(size_t)grow * 64 + c0] = o;
        }
    }
}

// ---------------- bagg1: bucket-LDS aggregate, 64 bf16 cols -----------------
// 1024 thr; wave handles 2 edges/iter via ushort2 (lanes 0-31 edge A, 32-63 B).
// x2[g] = relu(acc*nI + b1); nI from phase-A count.
__global__ __launch_bounds__(1024) void k_bagg1(const unsigned short* __restrict__ h,
        const int* __restrict__ ebuf, const int* __restrict__ bcur,
        const float* __restrict__ b1, float* __restrict__ x2,
        float* __restrict__ nI, int n) {
    __shared__ float acc[BNODES * 64];   // 32 KB
    __shared__ int cnt[BNODES];
    const int t = threadIdx.x, b = blockIdx.x;
    {
        float4* acc4 = (float4*)acc;
        acc4[t] = make_float4(0.f, 0.f, 0.f, 0.f);
        acc4[t + 1024] = make_float4(0.f, 0.f, 0.f, 0.f);
    }
    if (t < BNODES) cnt[t] = 0;
    __syncthreads();
    const int e0 = b * CAP, e1 = bcur[b * 16];
    // phase A: in-degree count (1 edge/thread)
    for (int i = e0 + t; i < e1; i += 1024) atomicAdd(&cnt[ebuf[i] >> 17], 1);
    __syncthreads();
    // phase B: gather + LDS accumulate, 2 edges per wave iteration
    const int wv = t >> 6, lane = t & 63;
    const int sub = lane >> 5, c2 = (lane & 31) * 2;
    for (int base = e0 + wv * 2; base + 1 < e1; base += 32) {
        int p = ebuf[base + sub];
        unsigned int hv = *(const unsigned int*)&h[(size_t)(p & SRCMASK) * 64 + c2];
        int row = p >> 17;
        atomicAdd(&acc[(row << 6) + c2],     __uint_as_float(hv << 16));
        atomicAdd(&acc[(row << 6) + c2 + 1], __uint_as_float(hv & 0xFFFF0000u));
    }
    if (((e1 - e0) & 1) && t < 32) {     // odd leftover edge
        int p = ebuf[e1 - 1];
        unsigned int hv = *(const unsigned int*)&h[(size_t)(p & SRCMASK) * 64 + t * 2];
        int row = p >> 17;
        atomicAdd(&acc[(row << 6) + t * 2],     __uint_as_float(hv << 16));
        atomicAdd(&acc[(row << 6) + t * 2 + 1], __uint_as_float(hv & 0xFFFF0000u));
    }
    __syncthreads();
    // epilogue: 8 cols/thread, coalesced float4 writes
    int row = t >> 3, coff = (t & 7) * 8;
    int g = b * BNODES + row;
    if (g < n) {
        float ni = rsqrtf(fmaxf((float)cnt[row], 1.0f));
        if (coff == 0) nI[g] = ni;
#pragma unroll
        for (int c = 0; c < 8; c += 4) {
            float4 a = *(float4*)&acc[(row << 6) + coff + c];
            float4 o;
            o.x = fmaxf(fmaf(a.x, ni, b1[coff + c + 0]), 0.f);
            o.y = fmaxf(fmaf(a.y, ni, b1[coff + c + 1]), 0.f);
            o.z = fmaxf(fmaf(a.z, ni, b1[coff + c + 2]), 0.f);
            o.w = fmaxf(fmaf(a.w, ni, b1[coff + c + 3]), 0.f);
            *(float4*)&x2[(size_t)g * 64 + coff + c] = o;
        }
    }
}

// ---------------- GEMM2: h2(bf16) = (x2*rsqrt(dO)) @ W2, 64->32 -------------
__global__ __launch_bounds__(256) void k_gemm2(const float* __restrict__ x2,
                        const float* __restrict__ W2, const int* __restrict__ dO,
                        unsigned short* __restrict__ h2, int n) {
    __shared__ float sX[128 * 68];
    __shared__ float sW[64 * 32];
    const int t = threadIdx.x;
    {
        const float4* W4 = (const float4*)W2;
        float4* sW4 = (float4*)sW;
#pragma unroll
        for (int i = 0; i < 2; i++) sW4[t + 256 * i] = W4[t + 256 * i];
    }
    const int rowbase = blockIdx.x * 128;
    {
        const float4* x4 = (const float4*)x2;
        float4* sX4 = (float4*)sX;
#pragma unroll
        for (int i = 0; i < 8; i++) {
            int f = t + 256 * i;
            int row = f >> 4, kc = f & 15;
            int grow = rowbase + row;
            float4 v = make_float4(0.f, 0.f, 0.f, 0.f);
            if (grow < n) v = x4[(size_t)grow * 16 + kc];
            sX4[row * 17 + kc] = v;
        }
    }
    __syncthreads();
    const int lane = t & 63, wv = t >> 6;
    const int whalf = wv >> 1, chalf = wv & 1;
    const int rg = lane >> 2, cg = lane & 3;
    const int c0 = chalf * 16 + cg * 4;
    const int rloc = whalf * 64 + rg;
    float acc[4][4] = {};
    for (int kk = 0; kk < 64; kk += 4) {
        float xr[4][4], wr[4][4];
#pragma unroll
        for (int i = 0; i < 4; i++)
            *(float4*)xr[i] = *(const float4*)&sX[(rloc + 16 * i) * 68 + kk];
#pragma unroll
        for (int j = 0; j < 4; j++)
            *(float4*)wr[j] = *(const float4*)&sW[(kk + j) * 32 + c0];
#pragma unroll
        for (int j = 0; j < 4; j++)
#pragma unroll
            for (int i = 0; i < 4; i++)
#pragma unroll
                for (int c = 0; c < 4; c++)
                    acc[i][c] = fmaf(xr[i][j], wr[j][c], acc[i][c]);
    }
#pragma unroll
    for (int i = 0; i < 4; i++) {
        int grow = rowbase + rloc + 16 * i;
        if (grow < n) {
            float nf = rsqrtf(fmaxf((float)dO[grow], 1.0f));
            ushort4 o;
            o.x = f2bf(acc[i][0] * nf); o.y = f2bf(acc[i][1] * nf);
            o.z = f2bf(acc[i][2] * nf); o.w = f2bf(acc[i][3] * nf);
            *(ushort4*)&h2[(size_t)grow * 32 + c0] = o;
        }
    }
}

// ---------------- bagg2: bucket-LDS aggregate, 32 bf16 cols -----------------
// wave handles 4 edges/iter via ushort2 (16 lanes per row).
__global__ __launch_bounds__(1024) void k_bagg2(const unsigned short* __restrict__ h,
        const int* __restrict__ ebuf, const int* __restrict__ bcur,
        const float* __restrict__ nI, const float* __restrict__ b2,
        float* __restrict__ out, int n) {
    __shared__ float acc[BNODES * 32];   // 16 KB
    const int t = threadIdx.x, b = blockIdx.x;
    ((float4*)acc)[t] = make_float4(0.f, 0.f, 0.f, 0.f);
    __syncthreads();
    const int e0 = b * CAP, e1 = bcur[b * 16];
    const int wv = t >> 6, lane = t & 63;
    const int sub = lane >> 4, c2 = (lane & 15) * 2;
    for (int base = e0 + wv * 4; base + 3 < e1; base += 64) {
        int p = ebuf[base + sub];
        unsigned int hv = *(const unsigned int*)&h[(size_t)(p & SRCMASK) * 32 + c2];
        int row = p >> 17;
        atomicAdd(&acc[(row << 5) + c2],     __uint_as_float(hv << 16));
        atomicAdd(&acc[(row << 5) + c2 + 1], __uint_as_float(hv & 0xFFFF0000u));
    }
    int rem = (e1 - e0) & 3;             // tail: last rem edges
    if (rem && t < rem * 16) {
        int p = ebuf[e1 - rem + (t >> 4)];
        int cc = (t & 15) * 2;
        unsigned int hv = *(const unsigned int*)&h[(size_t)(p & SRCMASK) * 32 + cc];
        int row = p >> 17;
        atomicAdd(&acc[(row << 5) + cc],     __uint_as_float(hv << 16));
        atomicAdd(&acc[(row << 5) + cc + 1], __uint_as_float(hv & 0xFFFF0000u));
    }
    __syncthreads();
    int row = t >> 3, coff = (t & 7) * 4;
    int g = b * BNODES + row;
    if (g < n) {
        float ni = nI[g];
        float4 a = *(float4*)&acc[(row << 5) + coff];
        float4 o;
        o.x = fmaf(a.x, ni, b2[coff + 0]);
        o.y = fmaf(a.y, ni, b2[coff + 1]);
        o.z = fmaf(a.z, ni, b2[coff + 2]);
        o.w = fmaf(a.w, ni, b2[coff + 3]);
        *(float4*)&out[(size_t)g * 32 + coff] = o;
    }
}

extern "C" void kernel_launch(void* const* d_in, const int* in_sizes, int n_in,
                              void* d_out, int out_size, void* d_ws, size_t ws_size,
                              hipStream_t stream) {
    const float* x   = (const float*)d_in[0];  // [N,128]
    const int*   src = (const int*)d_in[1];    // [E]
    const int*   dst = (const int*)d_in[2];    // [E]
    const float* W1  = (const float*)d_in[3];  // [128,64]
    const float* b1  = (const float*)d_in[4];  // [64]
    const float* W2  = (const float*)d_in[5];  // [64,32]
    const float* b2  = (const float*)d_in[6];  // [32]
    float* out = (float*)d_out;                // [N,32]

    const int N = in_sizes[0] / 128;           // 100000
    const int E = in_sizes[1];                 // 1600000
    const int NB = (N + BNODES - 1) / BNODES;  // 782 buckets

    char* wsb = (char*)d_ws;
    int*   dO   = (int*)wsb;    wsb += (size_t)N * 4;
    float* nI   = (float*)wsb;  wsb += (size_t)N * 4;
    int*   bcur = (int*)wsb;    wsb += (size_t)800 * 16 * 4;     // line-padded
    int*   ebuf = (int*)wsb;    wsb += (size_t)NB * CAP * 4;     // 8.0 MB (live through bagg2)
    unsigned short* h1 = (unsigned short*)wsb;
                                wsb += (size_t)N * 64 * 2;       // 12.8 MB bf16
    float* x2   = (float*)wsb;  wsb += (size_t)N * 64 * 4;       // 25.6 MB
    unsigned short* h2 = h1;    // h1 dead after k_bagg1

    hipMemsetAsync(dO, 0, (size_t)N * sizeof(int), stream);

    // binning (no per-node sort — aggregation consumes bucket streams directly)
    k_degO<<<(E + 255) / 256, 256, 0, stream>>>(src, dO, E);
    k_initcur<<<(NB + 255) / 256, 256, 0, stream>>>(bcur, NB);
    k_place<<<(E + 4095) / 4096, 1024, 0, stream>>>(src, dst, bcur, ebuf, E, NB);

    // layer 1
    k_gemm1<<<(N + 63) / 64, 256, 0, stream>>>(x, W1, dO, h1, N);
    k_bagg1<<<NB, 1024, 0, stream>>>(h1, ebuf, bcur, b1, x2, nI, N);

    // layer 2
    k_gemm2<<<(N + 127) / 128, 256, 0, stream>>>(x2, W2, dO, h2, N);
    k_bagg2<<<NB, 1024, 0, stream>>>(h2, ebuf, bcur, nI, b2, out, N);
}

// Round 12
// 359.096 us; speedup vs baseline: 3.4970x; 3.4970x over previous
//
#include <hip/hip_runtime.h>
#include <hip/hip_bf16.h>

// GNN: 2-layer GraphConv (DGL norm='both'), N=100000, E=1600000.
// Round 12: r10 structure restored (wave-per-node CSR gather — LDS-atomic
// aggregation is dead: r5 @21% occ and r11 @62% occ both cost ~680us,
// ~4cyc per f32 LDS-atomic value; per-lane serialized). New: agg kernels
// load uint (2 bf16 cols, full 4B/lane) with 2 edges/wave (agg64) or
// 4 edges/wave (agg32) per VMEM instr + shfl combine; degO fused into
// place's histogram phase (1024thr, fire-and-forget); bcur relative ->
// zero-init folded into one memset (k_degO + k_initcur dispatches gone).

#define BSH 7                 // 128 nodes per bucket
#define BNODES 128
#define SRCMASK 0x1FFFF       // src < 131072
#define CAP 2560              // bucket capacity (mean 2048, sigma~45)

__device__ __forceinline__ unsigned short f2bf(float f) {
    unsigned int u = __float_as_uint(f);
    return (unsigned short)((u + 0x7FFFu + ((u >> 16) & 1u)) >> 16);  // RNE
}

// ---------------- place: bin edges into fixed-cap bucket regions ------------
// 1024 thr, 4096-edge chunk. Phase 1 also counts out-degree (fire-and-forget
// 100k-target atomics, drained once at the barrier — NOT in the scatter chain,
// which was r9's 13.5%-occupancy mistake). bcur = relative counts (zero-init).
__global__ __launch_bounds__(1024) void k_place(const int* __restrict__ src,
        const int* __restrict__ dst, int* __restrict__ bcur,
        int* __restrict__ ebuf, int* __restrict__ dO, int E, int NB) {
    __shared__ int lh[800], lbase[800];
    int t = threadIdx.x;
    int e0 = blockIdx.x * 4096;
    int e1 = min(e0 + 4096, E);
    for (int i = t; i < NB; i += 1024) lh[i] = 0;
    __syncthreads();
    for (int i = e0 + t; i < e1; i += 1024) {
        atomicAdd(&lh[dst[i] >> BSH], 1);
        atomicAdd(&dO[src[i]], 1);
    }
    __syncthreads();
    for (int i = t; i < NB; i += 1024) {
        int c = lh[i];
        if (c) lbase[i] = atomicAdd(&bcur[i * 16], c);
        lh[i] = 0;
    }
    __syncthreads();
    for (int i = e0 + t; i < e1; i += 1024) {
        int d = dst[i], b = d >> BSH;
        int pos = b * CAP + lbase[b] + atomicAdd(&lh[b], 1);
        ebuf[pos] = src[i] | ((d & (BNODES - 1)) << 17);
    }
}

// ---------------- sort2: bucket stream -> per-node CSR + ostart/oend + nI ---
__global__ __launch_bounds__(1024) void k_sort2(const int* __restrict__ ebuf,
        const int* __restrict__ bcur, int* __restrict__ csrc,
        int* __restrict__ ostart, int* __restrict__ oend,
        float* __restrict__ nI, int n) {
    __shared__ int cnt[BNODES], cur[BNODES], s[BNODES];
    int t = threadIdx.x, b = blockIdx.x;
    int e0 = b * CAP, e1 = e0 + bcur[b * 16];
    if (t < BNODES) cnt[t] = 0;
    __syncthreads();
    for (int i = e0 + t; i < e1; i += 1024)
        atomicAdd(&cnt[ebuf[i] >> 17], 1);
    __syncthreads();
    if (t < BNODES) s[t] = cnt[t];
    __syncthreads();
    for (int o = 1; o < BNODES; o <<= 1) {
        int u = (t < BNODES && t >= o) ? s[t - o] : 0;
        __syncthreads();
        if (t < BNODES) s[t] += u;
        __syncthreads();
    }
    if (t < BNODES) {
        int st = e0 + s[t] - cnt[t];
        cur[t] = st;
        int g = b * BNODES + t;
        if (g < n) {
            ostart[g] = st;
            oend[g] = e0 + s[t];
            nI[g] = rsqrtf(fmaxf((float)cnt[t], 1.0f));
        }
    }
    __syncthreads();
    for (int i = e0 + t; i < e1; i += 1024) {
        int p = ebuf[i];
        int pos = atomicAdd(&cur[p >> 17], 1);
        csrc[pos] = p & SRCMASK;
    }
}

// ---------------- GEMM1: h1(bf16) = (x*rsqrt(dO)) @ W1, 128->64 -------------
__global__ __launch_bounds__(256) void k_gemm1(const float* __restrict__ x,
                        const float* __restrict__ W1, const int* __restrict__ dO,
                        unsigned short* __restrict__ h1, int n) {
    __shared__ float sX[64 * 132];
    __shared__ float sW[128 * 64];
    const int t = threadIdx.x;
    {
        const float4* W4 = (const float4*)W1;
        float4* sW4 = (float4*)sW;
#pragma unroll
        for (int i = 0; i < 8; i++) sW4[t + 256 * i] = W4[t + 256 * i];
    }
    const int rowbase = blockIdx.x * 64;
    {
        const float4* x4 = (const float4*)x;
        float4* sX4 = (float4*)sX;
#pragma unroll
        for (int i = 0; i < 8; i++) {
            int f = t + 256 * i;
            int row = f >> 5, kc = f & 31;
            int grow = rowbase + row;
            float4 v = make_float4(0.f, 0.f, 0.f, 0.f);
            if (grow < n) v = x4[(size_t)grow * 32 + kc];
            sX4[row * 33 + kc] = v;
        }
    }
    __syncthreads();
    const int lane = t & 63, wv = t >> 6;
    const int rg = lane >> 2, cg = lane & 3;
    const int c0 = wv * 16 + cg * 4;
    float acc[4][4] = {};
    for (int kk = 0; kk < 128; kk += 4) {
        float xr[4][4], wr[4][4];
#pragma unroll
        for (int i = 0; i < 4; i++)
            *(float4*)xr[i] = *(const float4*)&sX[(rg + 16 * i) * 132 + kk];
#pragma unroll
        for (int j = 0; j < 4; j++)
            *(float4*)wr[j] = *(const float4*)&sW[(kk + j) * 64 + c0];
#pragma unroll
        for (int j = 0; j < 4; j++)
#pragma unroll
            for (int i = 0; i < 4; i++)
#pragma unroll
                for (int c = 0; c < 4; c++)
                    acc[i][c] = fmaf(xr[i][j], wr[j][c], acc[i][c]);
    }
#pragma unroll
    for (int i = 0; i < 4; i++) {
        int grow = rowbase + rg + 16 * i;
        if (grow < n) {
            float nf = rsqrtf(fmaxf((float)dO[grow], 1.0f));
            ushort4 o;
            o.x = f2bf(acc[i][0] * nf); o.y = f2bf(acc[i][1] * nf);
            o.z = f2bf(acc[i][2] * nf); o.w = f2bf(acc[i][3] * nf);
            *(ushort4*)&h1[(size_t)grow * 64 + c0] = o;
        }
    }
}

// ---------------- agg1: wave per node, uint loads = 2 edges/VMEM ------------
// lanes: sub=lane>>5 picks edge A/B, c2=(lane&31)*2 picks col pair.
// Register accumulate; shfl-combine subs at the end. No atomics anywhere.
__global__ void k_agg64(const unsigned short* __restrict__ h,
                        const int* __restrict__ csrc,
                        const int* __restrict__ ostart, const int* __restrict__ oend,
                        const float* __restrict__ nI, const float* __restrict__ b1,
                        float* __restrict__ x2, int n) {
    int node = blockIdx.x * 4 + (threadIdx.x >> 6);
    int lane = threadIdx.x & 63;
    if (node >= n) return;
    int s0 = ostart[node], s1 = oend[node];
    int sub = lane >> 5;
    int c2 = (lane & 31) * 2;
    float a0 = 0.f, a1 = 0.f, a2 = 0.f, a3 = 0.f;
    int e = s0;
    for (; e + 3 < s1; e += 4) {                 // 4 edges, 2 loads/lane
        int p0 = csrc[e + sub];
        int p1 = csrc[e + 2 + sub];
        unsigned int hv0 = *(const unsigned int*)&h[(size_t)p0 * 64 + c2];
        unsigned int hv1 = *(const unsigned int*)&h[(size_t)p1 * 64 + c2];
        a0 += __uint_as_float(hv0 << 16);
        a1 += __uint_as_float(hv0 & 0xFFFF0000u);
        a2 += __uint_as_float(hv1 << 16);
        a3 += __uint_as_float(hv1 & 0xFFFF0000u);
    }
    for (; e < s1; e += 2) {
        if (e + sub < s1) {
            int p = csrc[e + sub];
            unsigned int hv = *(const unsigned int*)&h[(size_t)p * 64 + c2];
            a0 += __uint_as_float(hv << 16);
            a1 += __uint_as_float(hv & 0xFFFF0000u);
        }
    }
    a0 += a2; a1 += a3;
    a0 += __shfl(a0, lane ^ 32, 64);
    a1 += __shfl(a1, lane ^ 32, 64);
    if (sub == 0) {
        float ni = nI[node];
        float2 o;
        o.x = fmaxf(fmaf(a0, ni, b1[c2]), 0.f);
        o.y = fmaxf(fmaf(a1, ni, b1[c2 + 1]), 0.f);
        *(float2*)&x2[(size_t)node * 64 + c2] = o;
    }
}

// ---------------- GEMM2: h2(bf16) = (x2*rsqrt(dO)) @ W2, 64->32 -------------
__global__ __launch_bounds__(256) void k_gemm2(const float* __restrict__ x2,
                        const float* __restrict__ W2, const int* __restrict__ dO,
                        unsigned short* __restrict__ h2, int n) {
    __shared__ float sX[128 * 68];
    __shared__ float sW[64 * 32];
    const int t = threadIdx.x;
    {
        const float4* W4 = (const float4*)W2;
        float4* sW4 = (float4*)sW;
#pragma unroll
        for (int i = 0; i < 2; i++) sW4[t + 256 * i] = W4[t + 256 * i];
    }
    const int rowbase = blockIdx.x * 128;
    {
        const float4* x4 = (const float4*)x2;
        float4* sX4 = (float4*)sX;
#pragma unroll
        for (int i = 0; i < 8; i++) {
            int f = t + 256 * i;
            int row = f >> 4, kc = f & 15;
            int grow = rowbase + row;
            float4 v = make_float4(0.f, 0.f, 0.f, 0.f);
            if (grow < n) v = x4[(size_t)grow * 16 + kc];
            sX4[row * 17 + kc] = v;
        }
    }
    __syncthreads();
    const int lane = t & 63, wv = t >> 6;
    const int whalf = wv >> 1, chalf = wv & 1;
    const int rg = lane >> 2, cg = lane & 3;
    const int c0 = chalf * 16 + cg * 4;
    const int rloc = whalf * 64 + rg;
    float acc[4][4] = {};
    for (int kk = 0; kk < 64; kk += 4) {
        float xr[4][4], wr[4][4];
#pragma unroll
        for (int i = 0; i < 4; i++)
            *(float4*)xr[i] = *(const float4*)&sX[(rloc + 16 * i) * 68 + kk];
#pragma unroll
        for (int j = 0; j < 4; j++)
            *(float4*)wr[j] = *(const float4*)&sW[(kk + j) * 32 + c0];
#pragma unroll
        for (int j = 0; j < 4; j++)
#pragma unroll
            for (int i = 0; i < 4; i++)
#pragma unroll
                for (int c = 0; c < 4; c++)
                    acc[i][c] = fmaf(xr[i][j], wr[j][c], acc[i][c]);
    }
#pragma unroll
    for (int i = 0; i < 4; i++) {
        int grow = rowbase + rloc + 16 * i;
        if (grow < n) {
            float nf = rsqrtf(fmaxf((float)dO[grow], 1.0f));
            ushort4 o;
            o.x = f2bf(acc[i][0] * nf); o.y = f2bf(acc[i][1] * nf);
            o.z = f2bf(acc[i][2] * nf); o.w = f2bf(acc[i][3] * nf);
            *(ushort4*)&h2[(size_t)grow * 32 + c0] = o;
        }
    }
}

// ---------------- agg2: wave per node, uint loads = 4 edges/VMEM ------------
// sub=lane>>4 (0..3) picks edge, c2=(lane&15)*2 picks col pair.
__global__ void k_agg32(const unsigned short* __restrict__ h,
                        const int* __restrict__ csrc,
                        const int* __restrict__ ostart, const int* __restrict__ oend,
                        const float* __restrict__ nI, const float* __restrict__ b2,
                        float* __restrict__ out, int n) {
    int node = blockIdx.x * 4 + (threadIdx.x >> 6);
    int lane = threadIdx.x & 63;
    if (node >= n) return;
    int s0 = ostart[node], s1 = oend[node];
    int sub = lane >> 4;
    int c2 = (lane & 15) * 2;
    float a0 = 0.f, a1 = 0.f, a2 = 0.f, a3 = 0.f;
    int e = s0;
    for (; e + 7 < s1; e += 8) {                 // 8 edges, 2 loads/lane
        int p0 = csrc[e + sub];
        int p1 = csrc[e + 4 + sub];
        unsigned int hv0 = *(const unsigned int*)&h[(size_t)p0 * 32 + c2];
        unsigned int hv1 = *(const unsigned int*)&h[(size_t)p1 * 32 + c2];
        a0 += __uint_as_float(hv0 << 16);
        a1 += __uint_as_float(hv0 & 0xFFFF0000u);
        a2 += __uint_as_float(hv1 << 16);
        a3 += __uint_as_float(hv1 & 0xFFFF0000u);
    }
    for (; e < s1; e += 4) {
        if (e + sub < s1) {
            int p = csrc[e + sub];
            unsigned int hv = *(const unsigned int*)&h[(size_t)p * 32 + c2];
            a0 += __uint_as_float(hv << 16);
            a1 += __uint_as_float(hv & 0xFFFF0000u);
        }
    }
    a0 += a2; a1 += a3;
    a0 += __shfl(a0, lane ^ 16, 64);
    a1 += __shfl(a1, lane ^ 16, 64);
    a0 += __shfl(a0, lane ^ 32, 64);
    a1 += __shfl(a1, lane ^ 32, 64);
    if (sub == 0) {
        float ni = nI[node];
        float2 o;
        o.x = fmaf(a0, ni, b2[c2]);
        o.y = fmaf(a1, ni, b2[c2 + 1]);
        *(float2*)&out[(size_t)node * 32 + c2] = o;
    }
}

extern "C" void kernel_launch(void* const* d_in, const int* in_sizes, int n_in,
                              void* d_out, int out_size, void* d_ws, size_t ws_size,
                              hipStream_t stream) {
    const float* x   = (const float*)d_in[0];  // [N,128]
    const int*   src = (const int*)d_in[1];    // [E]
    const int*   dst = (const int*)d_in[2];    // [E]
    const float* W1  = (const float*)d_in[3];  // [128,64]
    const float* b1  = (const float*)d_in[4];  // [64]
    const float* W2  = (const float*)d_in[5];  // [64,32]
    const float* b2  = (const float*)d_in[6];  // [32]
    float* out = (float*)d_out;                // [N,32]

    const int N = in_sizes[0] / 128;           // 100000
    const int E = in_sizes[1];                 // 1600000
    const int NB = (N + BNODES - 1) / BNODES;  // 782 buckets

    char* wsb = (char*)d_ws;
    int*   dO     = (int*)wsb;    wsb += (size_t)N * 4;          // \ one memset
    int*   bcur   = (int*)wsb;    wsb += (size_t)800 * 16 * 4;   // / (contiguous)
    float* nI     = (float*)wsb;  wsb += (size_t)N * 4;
    int*   ostart = (int*)wsb;    wsb += (size_t)N * 4;
    int*   oend   = (int*)wsb;    wsb += (size_t)N * 4;
    int*   csrc   = (int*)wsb;    wsb += (size_t)NB * CAP * 4;   // 8.0 MB
    unsigned short* h1 = (unsigned short*)wsb;
                                  wsb += (size_t)N * 64 * 2;     // 12.8 MB bf16
    float* x2     = (float*)wsb;  wsb += (size_t)N * 64 * 4;     // 25.6 MB
    unsigned short* h2 = h1;      // h1 dead after k_agg64
    int*   ebuf   = (int*)x2;     // 8 MB region; dead before agg64 writes x2

    // one memset covers dO + bcur (adjacent, both need zeros)
    hipMemsetAsync(dO, 0, ((size_t)N + 800 * 16) * sizeof(int), stream);

    // CSR build (degO fused into place phase 1)
    k_place<<<(E + 4095) / 4096, 1024, 0, stream>>>(src, dst, bcur, ebuf, dO, E, NB);
    k_sort2<<<NB, 1024, 0, stream>>>(ebuf, bcur, csrc, ostart, oend, nI, N);

    // layer 1
    k_gemm1<<<(N + 63) / 64, 256, 0, stream>>>(x, W1, dO, h1, N);
    k_agg64<<<(N + 3) / 4, 256, 0, stream>>>(h1, csrc, ostart, oend, nI, b1, x2, N);

    // layer 2
    k_gemm2<<<(N + 127) / 128, 256, 0, stream>>>(x2, W2, dO, h2, N);
    k_agg32<<<(N + 3) / 4, 256, 0, stream>>>(h2, csrc, ostart, oend, nI, b2, out, N);
}